// Round 10
// baseline (36.486 us; speedup 1.0000x reference)
//
#include <hip/hip_runtime.h>

#define NCLS 24
#define NB 8
#define NCH 128
#define WLO 128
#define WHI 512
#define CELLS (128*128)
#define SUBT 256                    // subtiles (blocks) per batch
#define NBLK (NB * SUBT)            // 2048
#define KCH (NCLS * NCH)            // 3072
#define NF (NB * KCH)               // 24576

typedef _Float16 f16x8 __attribute__((ext_vector_type(8)));
typedef float    f32x4 __attribute__((ext_vector_type(4)));

// LDS-visibility barrier WITHOUT the vmcnt(0) drain (global DMAs ride through).
__device__ __forceinline__ void barrier_nodrain() {
    asm volatile("s_waitcnt lgkmcnt(0)" ::: "memory");
    __builtin_amdgcn_s_barrier();
}

// Direct global->LDS DMA, 16 B/lane, zero VGPR staging (compiler can't sink it).
__device__ __forceinline__ void load_lds16(const float* g, float* l) {
    __builtin_amdgcn_global_load_lds(
        (const __attribute__((address_space(1))) void*)g,
        (__attribute__((address_space(3))) void*)l, 16, 0, 0);
}

// One block = one 64-cell subtile. sums[32][128] = W[32][64] x T[64][128] via MFMA.
// tile is staged f32 by global_load_lds; each wave stages & consumes its OWN 32
// channels -> tile needs NO barrier, only a wave-local vmcnt(0).
__global__ __launch_bounds__(256, 4)
void fm_main(const float* __restrict__ data, const int* __restrict__ label,
             _Float16* __restrict__ part, float* __restrict__ cpart)
{
    __shared__ float tile[NCH * 64];          // 32 KB, [ch][cell] f32 linear
    __shared__ float histf[32 * 64];          // 8 KB, rows 24-31 stay zero (A-pad)

    const int bid  = blockIdx.x;
    const int b    = bid >> 8;
    const int grp  = bid & 255;               // subtile index
    const int tid  = threadIdx.x;

    const int w    = tid >> 6;        // wave id (= label hi-res row 0..3)
    const int lane = tid & 63;
    const int cl   = lane;            // label cell / histogram cell
    const int wb   = w * 32;          // this wave's channel base

    const int y  = grp >> 1;
    const int x0 = (grp & 1) << 6;
    const int cb = y * WLO + x0;

    // per-lane global base: cells offset folded in (lane&15)*4 cells * 4B
    const float* dbase = data + (size_t)b * NCH * CELLS + cb + (lane & 15) * 4;
    const int*   lbase = label + (size_t)b * (WHI * WHI) + (size_t)(4 * y + w) * WHI + x0 * 4;

    // ---- label load FIRST (its consumer runs first; keep it oldest in vmcnt) ----
    const int4 lv = *reinterpret_cast<const int4*>(lbase + cl * 4);
    __builtin_amdgcn_sched_barrier(0);   // pin order: lv before the DMAs

    // ---- bulk-issue 8 tile DMAs: instr k stages channels wb+4k..wb+4k+3 ----
#pragma unroll
    for (int k = 0; k < 8; ++k)
        load_lds16(dbase + (size_t)(wb + k * 4 + (lane >> 4)) * CELLS,
                   &tile[(wb + k * 4) * 64]);

    // ---- zero histogram (2048 f32 = 512 float4) ----
    reinterpret_cast<f32x4*>(histf)[tid]       = (f32x4){0.f, 0.f, 0.f, 0.f};
    reinterpret_cast<f32x4*>(histf)[tid + 256] = (f32x4){0.f, 0.f, 0.f, 0.f};
    barrier_nodrain();                         // B1: zeros visible; DMAs in flight

    // ---- histogram atomics (waits vmcnt for lv only — lv is oldest) ----
    if ((unsigned)lv.x < 24u) atomicAdd(&histf[lv.x * 64 + cl], 1.f);
    if ((unsigned)lv.y < 24u) atomicAdd(&histf[lv.y * 64 + cl], 1.f);
    if ((unsigned)lv.z < 24u) atomicAdd(&histf[lv.z * 64 + cl], 1.f);
    if ((unsigned)lv.w < 24u) atomicAdd(&histf[lv.w * 64 + cl], 1.f);
    barrier_nodrain();                         // B2: all atomics retired

    // ---- A fragments from f32 histogram (cvt in regs); counts from same reads ----
    f16x8 af[2][2];
    float cs0 = 0.f, cs1 = 0.f;
#pragma unroll
    for (int mt = 0; mt < 2; ++mt)
#pragma unroll
        for (int kt = 0; kt < 2; ++kt) {
            const int cls = mt * 16 + (lane & 15);
            const int e0  = kt * 32 + (lane >> 4) * 8;
            const float* hp = &histf[cls * 64 + e0];
            const f32x4 h0 = *reinterpret_cast<const f32x4*>(hp);
            const f32x4 h1 = *reinterpret_cast<const f32x4*>(hp + 4);
            f16x8 a;
            a[0] = (_Float16)h0.x; a[1] = (_Float16)h0.y; a[2] = (_Float16)h0.z; a[3] = (_Float16)h0.w;
            a[4] = (_Float16)h1.x; a[5] = (_Float16)h1.y; a[6] = (_Float16)h1.z; a[7] = (_Float16)h1.w;
            af[mt][kt] = a;
            const float p = (h0.x + h0.y) + (h0.z + h0.w) + (h1.x + h1.y) + (h1.z + h1.w);
            if (mt == 0) cs0 += p; else cs1 += p;
        }

    // ---- wave-local wait for OWN tile DMAs (no barrier needed: channels private) ----
    asm volatile("s_waitcnt vmcnt(0)" ::: "memory");

    // ---- B fragments from f32 tile, cvt to f16 ----
    f16x8 bf[2][2];
#pragma unroll
    for (int nt = 0; nt < 2; ++nt)
#pragma unroll
        for (int kt = 0; kt < 2; ++kt) {
            const int row = wb + nt * 16 + (lane & 15);
            const float* tp = &tile[row * 64 + kt * 32 + (lane >> 4) * 8];
            const f32x4 b0 = *reinterpret_cast<const f32x4*>(tp);
            const f32x4 b1 = *reinterpret_cast<const f32x4*>(tp + 4);
            f16x8 v;
            v[0] = (_Float16)b0.x; v[1] = (_Float16)b0.y; v[2] = (_Float16)b0.z; v[3] = (_Float16)b0.w;
            v[4] = (_Float16)b1.x; v[5] = (_Float16)b1.y; v[6] = (_Float16)b1.z; v[7] = (_Float16)b1.w;
            bf[nt][kt] = v;
        }

    // ---- 8 MFMAs ----
    f32x4 acc[2][2];
#pragma unroll
    for (int mt = 0; mt < 2; ++mt)
#pragma unroll
        for (int nt = 0; nt < 2; ++nt) {
            acc[mt][nt] = (f32x4){0.f, 0.f, 0.f, 0.f};
#pragma unroll
            for (int kt = 0; kt < 2; ++kt)
                acc[mt][nt] = __builtin_amdgcn_mfma_f32_16x16x32_f16(
                    af[mt][kt], bf[nt][kt], acc[mt][nt], 0, 0, 0);
        }

    // ---- counts: butterfly over 4 k-groups; wave 0 lanes write ----
    cs0 += __shfl_xor(cs0, 16, 64); cs0 += __shfl_xor(cs0, 32, 64);
    cs1 += __shfl_xor(cs1, 16, 64); cs1 += __shfl_xor(cs1, 32, 64);
    if (w == 0 && lane < 16) {
        cpart[(size_t)bid * NCLS + lane] = cs0;
        if (lane < 8) cpart[(size_t)bid * NCLS + 16 + lane] = cs1;
    }

    // ---- flush f16 per-block partials (non-atomic) ----
    _Float16* pblk = part + (size_t)bid * KCH;
#pragma unroll
    for (int mt = 0; mt < 2; ++mt)
#pragma unroll
        for (int nt = 0; nt < 2; ++nt)
#pragma unroll
            for (int rg = 0; rg < 4; ++rg) {
                const int cls = mt * 16 + (lane >> 4) * 4 + rg;   // C/D: row=(lane>>4)*4+reg
                const int ch  = wb + nt * 16 + (lane & 15);       //      col=lane&15
                if (cls < NCLS) pblk[cls * NCH + ch] = (_Float16)acc[mt][nt][rg];
            }
}

// Grid 384 = (b, cls, ch-half). 4 waves reduce 64 g's each -> LDS -> wave-0 finish.
__global__ __launch_bounds__(256)
void fm_final(const _Float16* __restrict__ part, const float* __restrict__ cpart,
              float* __restrict__ out)
{
    __shared__ float red[256];
    __shared__ float credv[256];
    const int bid  = blockIdx.x;
    const int b    = bid / (NCLS * 2);
    const int rem  = bid % (NCLS * 2);
    const int cls  = rem >> 1;
    const int half = rem & 1;
    const int t    = threadIdx.x;
    const int c    = t & 63;           // channel within half
    const int gq   = t >> 6;           // g-quarter 0..3

    credv[t] = cpart[(size_t)(b * SUBT + t) * NCLS + cls];

    const _Float16* pb = part + (size_t)(b * SUBT + gq * 64) * KCH + cls * NCH + half * 64 + c;
    float s = 0.f;
#pragma unroll 8
    for (int g = 0; g < 64; ++g) s += (float)pb[(size_t)g * KCH];
    red[t] = s;
    __syncthreads();

    if (t < 64) {
        float cnt = credv[t] + credv[t + 64] + credv[t + 128] + credv[t + 192];
#pragma unroll
        for (int o = 32; o >= 1; o >>= 1) cnt += __shfl_xor(cnt, o, 64);
        const float sf = red[t] + red[t + 64] + red[t + 128] + red[t + 192];
        out[(size_t)b * KCH + (half * 64 + t) * NCLS + cls] = sf / (cnt + 1e-8f);  // (B,C,NCLS)
        if (t == 0 && half == 0) out[NF + b * NCLS + cls] = (cnt > 0.f) ? 1.f : 0.f;
    }
}

extern "C" void kernel_launch(void* const* d_in, const int* in_sizes, int n_in,
                              void* d_out, int out_size, void* d_ws, size_t ws_size,
                              hipStream_t stream) {
    const float* data  = (const float*)d_in[0];
    const int*   label = (const int*)d_in[1];
    float*     out   = (float*)d_out;
    _Float16*  part  = (_Float16*)d_ws;                          // NBLK*3072 f16 (12.6 MB)
    float*     cpart = (float*)(part + (size_t)NBLK * KCH);      // NBLK*24 f32

    fm_main<<<dim3(NBLK), dim3(256), 0, stream>>>(data, label, part, cpart);
    fm_final<<<dim3(NB * NCLS * 2), dim3(256), 0, stream>>>(part, cpart, out);
}

// Round 11
// 36.363 us; speedup vs baseline: 1.0034x; 1.0034x over previous
//
#include <hip/hip_runtime.h>

#define NCLS 24
#define NB 8
#define NCH 128
#define WHI 512
#define CELLS (128*128)              // 16384 cells per batch
#define CPB 256                      // cells per block (kernels A and B)
#define KBLK 64                      // blocks per batch = CELLS/CPB
#define NBLK (NB * KBLK)             // 512
#define MROW 32                      // padded class rows for MFMA
#define KCH (NCH * NCLS)             // 3072
#define NF (NB * KCH)                // 24576
#define RP 129                       // LDS reduce row pitch (floats) - bank spread
#define WSTR ((size_t)MROW * CELLS)  // W per-batch stride (f16 elems)

typedef _Float16 f16x8 __attribute__((ext_vector_type(8)));
typedef float    f32x4 __attribute__((ext_vector_type(4)));

// ---------------- Kernel A: labels -> W[b][32][16384] f16 + count partials ----
// Block = 256 cells. LDS hist column t is PRIVATE to thread t -> atomics never
// contend, W store needs no barrier. 3 barriers total (zero + count reduce).
__global__ __launch_bounds__(256)
void fm_wcount(const int* __restrict__ label, _Float16* __restrict__ W,
               float* __restrict__ cpart)
{
    __shared__ float h[NCLS * 257];      // [cls][cell-in-block], pitch 257
    __shared__ float ps[NCLS * 8];
    const int bid = blockIdx.x, b = bid >> 6, cblk = bid & 63;
    const int t = threadIdx.x;
    const int cell = cblk * 256 + t;
    const int y = cell >> 7, x = cell & 127;

#pragma unroll
    for (int k = 0; k < 25; ++k) {
        const int idx = t + k * 256;
        if (idx < NCLS * 257) h[idx] = 0.f;
    }
    __syncthreads();

    const int* lp = label + (size_t)b * (WHI * WHI) + (size_t)(4 * y) * WHI + 4 * x;
    const int4 L0 = *(const int4*)lp;
    const int4 L1 = *(const int4*)(lp + WHI);
    const int4 L2 = *(const int4*)(lp + 2 * WHI);
    const int4 L3 = *(const int4*)(lp + 3 * WHI);
#define AH(v) if ((unsigned)(v) < 24u) atomicAdd(&h[(v) * 257 + t], 1.f)
    AH(L0.x); AH(L0.y); AH(L0.z); AH(L0.w);
    AH(L1.x); AH(L1.y); AH(L1.z); AH(L1.w);
    AH(L2.x); AH(L2.y); AH(L2.z); AH(L2.w);
    AH(L3.x); AH(L3.y); AH(L3.z); AH(L3.w);
#undef AH

    // W store: own column only -> no barrier needed (lgkmcnt dep handled by compiler)
#pragma unroll
    for (int cls = 0; cls < NCLS; ++cls)
        W[(size_t)b * WSTR + (size_t)cls * CELLS + cell] = (_Float16)h[cls * 257 + t];

    __syncthreads();
    if (t < 192) {
        const int cls = t >> 3, seg = t & 7;
        float s = 0.f;
#pragma unroll
        for (int m = 0; m < 32; ++m) s += h[cls * 257 + seg + 8 * m];
        ps[cls * 8 + seg] = s;
    }
    __syncthreads();
    if (t < NCLS) {
        float s = 0.f;
#pragma unroll
        for (int g = 0; g < 8; ++g) s += ps[t * 8 + g];
        cpart[bid * NCLS + t] = s;
    }
}

// ---------------- Kernel B: barrier-free streaming GEMM slice ----------------
// Wave = (b, 64 cells, all 128 ch). A,B fragments straight from global (36
// independent loads bulk-issued), 32 MFMAs, one end-of-kernel LDS reduce.
__global__ __launch_bounds__(256, 2)
void fm_gemm(const float* __restrict__ data, const _Float16* __restrict__ W,
             _Float16* __restrict__ part)
{
    __shared__ float red[4 * MROW * RP];   // 66048 B -> 2 blocks/CU
    const int bid = blockIdx.x, b = bid >> 6, kblk = bid & 63;
    const int tid = threadIdx.x, w = tid >> 6, l = tid & 63;
    const int l15 = l & 15, lg = l >> 4;
    const int c0 = kblk * CPB + w * 64;

    // ---- A fragments: W[cls = mt*16+l15][c0 + kt*32 + lg*8 ..+8] (16 B/lane) ----
    f16x8 af[2][2];
#pragma unroll
    for (int mt = 0; mt < 2; ++mt)
#pragma unroll
        for (int kt = 0; kt < 2; ++kt)
            af[mt][kt] = *(const f16x8*)(W + (size_t)b * WSTR
                                           + (size_t)(mt * 16 + l15) * CELLS
                                           + c0 + kt * 32 + lg * 8);

    // ---- B staging: data[ch = n*16+l15][c0 + kt*32 + lg*8 ..+8] f32, bulk-issued ----
    f32x4 bs[2][8][2];
#pragma unroll
    for (int kt = 0; kt < 2; ++kt)
#pragma unroll
        for (int n = 0; n < 8; ++n)
#pragma unroll
            for (int p = 0; p < 2; ++p)
                bs[kt][n][p] = *(const f32x4*)(data + (size_t)(b * NCH + n * 16 + l15) * CELLS
                                                 + c0 + kt * 32 + lg * 8 + p * 4);
    __builtin_amdgcn_sched_barrier(0);   // keep all loads issued up-front (don't sink)

    f32x4 acc[2][8];
#pragma unroll
    for (int mt = 0; mt < 2; ++mt)
#pragma unroll
        for (int n = 0; n < 8; ++n) acc[mt][n] = (f32x4){0.f, 0.f, 0.f, 0.f};

#pragma unroll
    for (int kt = 0; kt < 2; ++kt)
#pragma unroll
        for (int n = 0; n < 8; ++n) {
            f16x8 bf;
            bf[0] = (_Float16)bs[kt][n][0].x; bf[1] = (_Float16)bs[kt][n][0].y;
            bf[2] = (_Float16)bs[kt][n][0].z; bf[3] = (_Float16)bs[kt][n][0].w;
            bf[4] = (_Float16)bs[kt][n][1].x; bf[5] = (_Float16)bs[kt][n][1].y;
            bf[6] = (_Float16)bs[kt][n][1].z; bf[7] = (_Float16)bs[kt][n][1].w;
            acc[0][n] = __builtin_amdgcn_mfma_f32_16x16x32_f16(af[0][kt], bf, acc[0][n], 0, 0, 0);
            acc[1][n] = __builtin_amdgcn_mfma_f32_16x16x32_f16(af[1][kt], bf, acc[1][n], 0, 0, 0);
        }

    // ---- cross-wave LDS reduce (ONE barrier) ----
    float* rw = &red[w * MROW * RP];
#pragma unroll
    for (int mt = 0; mt < 2; ++mt)
#pragma unroll
        for (int n = 0; n < 8; ++n)
#pragma unroll
            for (int rg = 0; rg < 4; ++rg)     // C/D: row = (lane>>4)*4+reg, col = lane&15
                rw[(mt * 16 + lg * 4 + rg) * RP + n * 16 + l15] = acc[mt][n][rg];
    __syncthreads();

    const int p = tid & 63, clsg = tid >> 6;
#pragma unroll
    for (int i = 0; i < 8; ++i) {
        const int cls = clsg * 8 + i;
        if (cls < NCLS) {
            float s0 = 0.f, s1 = 0.f;
#pragma unroll
            for (int wv = 0; wv < 4; ++wv) {
                s0 += red[wv * MROW * RP + cls * RP + 2 * p];
                s1 += red[wv * MROW * RP + cls * RP + 2 * p + 1];
            }
            const _Float16 h0 = (_Float16)s0, h1 = (_Float16)s1;
            unsigned u = (unsigned)*(const unsigned short*)&h0
                       | ((unsigned)*(const unsigned short*)&h1 << 16);
            *(unsigned*)(part + (size_t)bid * 4096 + cls * 128 + 2 * p) = u;
        }
    }
}

// ---------------- Kernel C: reduce 64 partials + divide + mask ---------------
__global__ __launch_bounds__(256)
void fm_final(const _Float16* __restrict__ part, const float* __restrict__ cpart,
              float* __restrict__ out)
{
    __shared__ float red[256];
    __shared__ float credv[64];
    const int bid = blockIdx.x;
    const int b = bid / (NCLS * 2), rem = bid % (NCLS * 2);
    const int cls = rem >> 1, half = rem & 1;
    const int t = threadIdx.x, c = t & 63, gq = t >> 6;

    if (t < 64) credv[t] = cpart[(b * 64 + t) * NCLS + cls];

    const _Float16* pb = part + (size_t)(b * 64 + gq * 16) * 4096 + cls * 128 + half * 64 + c;
    float s = 0.f;
#pragma unroll
    for (int m = 0; m < 16; ++m) s += (float)pb[(size_t)m * 4096];
    red[t] = s;
    __syncthreads();

    if (t < 64) {
        float cnt = credv[t];
#pragma unroll
        for (int o = 32; o >= 1; o >>= 1) cnt += __shfl_xor(cnt, o, 64);
        const float sf = red[t] + red[t + 64] + red[t + 128] + red[t + 192];
        out[(size_t)b * KCH + (half * 64 + t) * NCLS + cls] = sf / (cnt + 1e-8f);  // (B,C,NCLS)
        if (t == 0 && half == 0) out[NF + b * NCLS + cls] = (cnt > 0.f) ? 1.f : 0.f;
    }
}

extern "C" void kernel_launch(void* const* d_in, const int* in_sizes, int n_in,
                              void* d_out, int out_size, void* d_ws, size_t ws_size,
                              hipStream_t stream) {
    const float* data  = (const float*)d_in[0];
    const int*   label = (const int*)d_in[1];
    float* out = (float*)d_out;

    _Float16* W     = (_Float16*)d_ws;                       // 8*32*16384 f16 = 8 MB
    _Float16* part  = W + (size_t)NB * WSTR;                 // 512*4096 f16 = 4 MB
    float*    cpart = (float*)(part + (size_t)NBLK * 4096);  // 512*24 f32

    fm_wcount<<<dim3(NBLK), dim3(256), 0, stream>>>(label, W, cpart);
    fm_gemm  <<<dim3(NBLK), dim3(256), 0, stream>>>(data, W, part);
    fm_final <<<dim3(NB * NCLS * 2), dim3(256), 0, stream>>>(part, cpart, out);
}